// Round 7
// baseline (46.680 us; speedup 1.0000x reference)
//
#include <hip/hip_runtime.h>
#include <stdint.h>
#include <math.h>

#define BN 16
#define LATN 64
#define STATSN 7
#define ZN 71
#define HN 128
#define H2N 256
#define NNODE 256
#define NPAIR 32640            // N*(N-1)/2
#define NQ 522240              // BN*NPAIR

// compiler reorder fence (single-wave kernel: HW DS ordering is in-order per
// wave; this only stops the compiler from moving LDS reads above writes)
#define FENCE() asm volatile("" ::: "memory")

// ---------------- Threefry-2x32, 20 rounds, key = (0, 42) ----------------
__device__ __forceinline__ void tf2x32(uint32_t x0, uint32_t x1,
                                       uint32_t& o0, uint32_t& o1) {
    const uint32_t ks0 = 0u, ks1 = 42u, ks2 = 0x1BD11BF0u;  // 0^42^0x1BD11BDA
    x0 += ks0; x1 += ks1;
#define TFRND(r) { x0 += x1; x1 = (x1 << (r)) | (x1 >> (32 - (r))); x1 ^= x0; }
    TFRND(13) TFRND(15) TFRND(26) TFRND(6)
    x0 += ks1; x1 += ks2 + 1u;
    TFRND(17) TFRND(29) TFRND(16) TFRND(24)
    x0 += ks2; x1 += ks0 + 2u;
    TFRND(13) TFRND(15) TFRND(26) TFRND(6)
    x0 += ks0; x1 += ks1 + 3u;
    TFRND(17) TFRND(29) TFRND(16) TFRND(24)
    x0 += ks1; x1 += ks2 + 4u;
    TFRND(13) TFRND(15) TFRND(26) TFRND(6)
    x0 += ks2; x1 += ks0 + 5u;
#undef TFRND
    o0 = x0; o1 = x1;
}

__device__ __forceinline__ uint32_t bits_partitionable(uint32_t m) {
    uint32_t o0, o1;
    tf2x32(0u, m, o0, o1);
    return o0 ^ o1;
}

__device__ __forceinline__ float bits_to_u(uint32_t w) {
    float f = __uint_as_float((w >> 9) | 0x3f800000u) - 1.0f;
    const float mn = 1e-9f;
    return fmaxf(mn, f * (1.0f - mn) + mn);
}

// ---------------- LN stats: butterfly over the single wave ----------------
// identical arithmetic to round-6 w0_stats (passed with absmax 0)
template<int NV>
__device__ __forceinline__ void lane_stats(const float* v, double& m, double& rs) {
    double a = 0.0, q = 0.0;
#pragma unroll
    for (int i = 0; i < NV; ++i) {
        a += (double)v[i];
        q += (double)v[i] * (double)v[i];
    }
#pragma unroll
    for (int s = 1; s < 64; s <<= 1) {
        a += __shfl_xor(a, s, 64);
        q += __shfl_xor(q, s, 64);
    }
    constexpr double O = (double)(NV * 64);
    m = a * (1.0 / O);
    const double var = q * (1.0 / O) - m * m;
    rs = 1.0 / sqrt(var + 1e-5);
}

// ---------------- dots: lane owns adjacent outputs (coalesced W loads) ------
// O=128, lane owns outputs {2l, 2l+1}; W row-major [K][128]
template<int K>
__device__ __forceinline__ void dot2(const float* __restrict__ W,
                                     const float* __restrict__ V, int l,
                                     double& A, double& B) {
    double a0 = 0, a1 = 0, a2 = 0, a3 = 0, b0 = 0, b1 = 0, b2 = 0, b3 = 0;
#pragma unroll 8
    for (int k = 0; k < K; k += 4) {
        const float4 v4 = *reinterpret_cast<const float4*>(&V[k]);
        const float2 w0 = *reinterpret_cast<const float2*>(&W[(k + 0) * HN + 2 * l]);
        const float2 w1 = *reinterpret_cast<const float2*>(&W[(k + 1) * HN + 2 * l]);
        const float2 w2 = *reinterpret_cast<const float2*>(&W[(k + 2) * HN + 2 * l]);
        const float2 w3 = *reinterpret_cast<const float2*>(&W[(k + 3) * HN + 2 * l]);
        a0 = fma((double)v4.x, (double)w0.x, a0); b0 = fma((double)v4.x, (double)w0.y, b0);
        a1 = fma((double)v4.y, (double)w1.x, a1); b1 = fma((double)v4.y, (double)w1.y, b1);
        a2 = fma((double)v4.z, (double)w2.x, a2); b2 = fma((double)v4.z, (double)w2.y, b2);
        a3 = fma((double)v4.w, (double)w3.x, a3); b3 = fma((double)v4.w, (double)w3.y, b3);
    }
    A = (a0 + a1) + (a2 + a3);
    B = (b0 + b1) + (b2 + b3);
}

// input_proj: O=256, lane owns {4l..4l+3}; K=71; W [71][256]
__device__ __forceinline__ void dot4_ip(const float* __restrict__ W,
                                        const float* __restrict__ V, int l,
                                        double* out) {
    double ca[4] = {0, 0, 0, 0}, cb[4] = {0, 0, 0, 0};
#pragma unroll
    for (int k = 0; k < 70; k += 2) {
        const float4 w0 = *reinterpret_cast<const float4*>(&W[(k + 0) * H2N + 4 * l]);
        const float4 w1 = *reinterpret_cast<const float4*>(&W[(k + 1) * H2N + 4 * l]);
        const float v0 = V[k], v1 = V[k + 1];
        ca[0] = fma((double)v0, (double)w0.x, ca[0]); cb[0] = fma((double)v1, (double)w1.x, cb[0]);
        ca[1] = fma((double)v0, (double)w0.y, ca[1]); cb[1] = fma((double)v1, (double)w1.y, cb[1]);
        ca[2] = fma((double)v0, (double)w0.z, ca[2]); cb[2] = fma((double)v1, (double)w1.z, cb[2]);
        ca[3] = fma((double)v0, (double)w0.w, ca[3]); cb[3] = fma((double)v1, (double)w1.w, cb[3]);
    }
    {   // k = 70 tail
        const float4 wt = *reinterpret_cast<const float4*>(&W[70 * H2N + 4 * l]);
        const float vt = V[70];
        ca[0] = fma((double)vt, (double)wt.x, ca[0]);
        ca[1] = fma((double)vt, (double)wt.y, ca[1]);
        ca[2] = fma((double)vt, (double)wt.z, ca[2]);
        ca[3] = fma((double)vt, (double)wt.w, ca[3]);
    }
#pragma unroll
    for (int i = 0; i < 4; ++i) out[i] = ca[i] + cb[i];
}

// one wave (64 threads) per batch; zero barriers
__global__ __launch_bounds__(64) void logits_kernel(
    const float* __restrict__ x, const float* __restrict__ st,
    const float* __restrict__ ipw, const float* __restrict__ ipb,
    const float* __restrict__ ipg, const float* __restrict__ ipbb,
    const float* __restrict__ drw, const float* __restrict__ drb,
    const float* __restrict__ drg, const float* __restrict__ drbb,
    const float* __restrict__ r1w, const float* __restrict__ r1b,
    const float* __restrict__ r2w, const float* __restrict__ r2b,
    const float* __restrict__ n1g, const float* __restrict__ n1b,
    const float* __restrict__ n2g, const float* __restrict__ n2b,
    const float* __restrict__ e1w, const float* __restrict__ e1b,
    const float* __restrict__ eg,  const float* __restrict__ eb,
    const float* __restrict__ e2w, const float* __restrict__ e2b,
    float* __restrict__ out_logits)
{
    __shared__ __align__(16) float V0[H2N];
    __shared__ __align__(16) float V1[H2N];
    const int l = threadIdx.x;     // 0..63
    const int b = blockIdx.x;

    // -------- prologue: per-lane parameter registers (coalesced vec loads) ----
    const float4 ipb4  = *reinterpret_cast<const float4*>(&ipb[4 * l]);
    const float4 ipg4  = *reinterpret_cast<const float4*>(&ipg[4 * l]);
    const float4 ipbb4 = *reinterpret_cast<const float4*>(&ipbb[4 * l]);
    const float2 drb2  = *reinterpret_cast<const float2*>(&drb[2 * l]);
    const float2 drg2  = *reinterpret_cast<const float2*>(&drg[2 * l]);
    const float2 drbb2 = *reinterpret_cast<const float2*>(&drbb[2 * l]);
    const float2 b1a = *reinterpret_cast<const float2*>(&r1b[2 * l]);
    const float2 g1a = *reinterpret_cast<const float2*>(&n1g[2 * l]);
    const float2 c1a = *reinterpret_cast<const float2*>(&n1b[2 * l]);
    const float2 g2a = *reinterpret_cast<const float2*>(&n2g[2 * l]);
    const float2 c2a = *reinterpret_cast<const float2*>(&n2b[2 * l]);
    const float2 b2a = *reinterpret_cast<const float2*>(&r2b[2 * l]);
    const float2 b1b = *reinterpret_cast<const float2*>(&r1b[HN + 2 * l]);
    const float2 g1b = *reinterpret_cast<const float2*>(&n1g[HN + 2 * l]);
    const float2 c1b = *reinterpret_cast<const float2*>(&n1b[HN + 2 * l]);
    const float2 g2b = *reinterpret_cast<const float2*>(&n2g[HN + 2 * l]);
    const float2 c2b = *reinterpret_cast<const float2*>(&n2b[HN + 2 * l]);
    const float2 b2b = *reinterpret_cast<const float2*>(&r2b[HN + 2 * l]);
    const float2 e1b2 = *reinterpret_cast<const float2*>(&e1b[2 * l]);
    const float2 eg2  = *reinterpret_cast<const float2*>(&eg[2 * l]);
    const float2 eb2  = *reinterpret_cast<const float2*>(&eb[2 * l]);
    const float2 e2wA = *reinterpret_cast<const float2*>(&e2w[2 * l]);        // k=l
    const float2 e2wB = *reinterpret_cast<const float2*>(&e2w[HN + 2 * l]);   // k=l+64

    // -------- stage z --------
    V0[l] = x[b * LATN + l];
    if (l < STATSN) V0[LATN + l] = st[b * STATSN + l];
    FENCE();

    // -------- input_proj: [71]->relu->LN(256) -> V1 --------
    {
        double a4[4];
        dot4_ip(ipw, V0, l, a4);
        float v4[4];
#pragma unroll
        for (int i = 0; i < 4; ++i) {
            const float bias = (i == 0) ? ipb4.x : (i == 1) ? ipb4.y : (i == 2) ? ipb4.z : ipb4.w;
            v4[i] = fmaxf((float)a4[i] + bias, 0.0f);
        }
        double m, rs;
        lane_stats<4>(v4, m, rs);
        float o0 = (float)(((double)v4[0] - m) * rs) * ipg4.x + ipbb4.x;
        float o1 = (float)(((double)v4[1] - m) * rs) * ipg4.y + ipbb4.y;
        float o2 = (float)(((double)v4[2] - m) * rs) * ipg4.z + ipbb4.z;
        float o3 = (float)(((double)v4[3] - m) * rs) * ipg4.w + ipbb4.w;
        *reinterpret_cast<float4*>(&V1[4 * l]) = make_float4(o0, o1, o2, o3);
    }
    FENCE();

    // -------- dim_reduce: [256]->[128], relu, LN -> h in regs --------
    float h0, h1;
    {
        double A, B;
        dot2<H2N>(drw, V1, l, A, B);
        float v2[2];
        v2[0] = fmaxf((float)A + drb2.x, 0.0f);
        v2[1] = fmaxf((float)B + drb2.y, 0.0f);
        double m, rs;
        lane_stats<2>(v2, m, rs);
        h0 = (float)(((double)v2[0] - m) * rs) * drg2.x + drbb2.x;
        h1 = (float)(((double)v2[1] - m) * rs) * drg2.y + drbb2.y;
    }

    // -------- residual block 0 --------
    {
        float hv[2] = {h0, h1};
        double m, rs;
        lane_stats<2>(hv, m, rs);   // LN1 over h
        V1[2 * l]     = (float)(((double)h0 - m) * rs) * g1a.x + c1a.x;
        V1[2 * l + 1] = (float)(((double)h1 - m) * rs) * g1a.y + c1a.y;
        FENCE();
        double A, B;
        dot2<HN>(r1w, V1, l, A, B);   // lin1
        float v2[2];
        v2[0] = fmaxf((float)A + b1a.x, 0.0f);
        v2[1] = fmaxf((float)B + b1a.y, 0.0f);
        lane_stats<2>(v2, m, rs);     // LN2
        FENCE();
        V1[2 * l]     = (float)(((double)v2[0] - m) * rs) * g2a.x + c2a.x;
        V1[2 * l + 1] = (float)(((double)v2[1] - m) * rs) * g2a.y + c2a.y;
        FENCE();
        dot2<HN>(r2w, V1, l, A, B);   // lin2
        float r2o0 = (float)A + b2a.x;
        float r2o1 = (float)B + b2a.y;
        h0 = h0 + 0.1f * (r2o0 + h0);
        h1 = h1 + 0.1f * (r2o1 + h1);
    }

    // -------- residual block 1 --------
    {
        float hv[2] = {h0, h1};
        double m, rs;
        lane_stats<2>(hv, m, rs);   // LN1
        FENCE();
        V1[2 * l]     = (float)(((double)h0 - m) * rs) * g1b.x + c1b.x;
        V1[2 * l + 1] = (float)(((double)h1 - m) * rs) * g1b.y + c1b.y;
        FENCE();
        double A, B;
        dot2<HN>(r1w + HN * HN, V1, l, A, B);   // lin1
        float v2[2];
        v2[0] = fmaxf((float)A + b1b.x, 0.0f);
        v2[1] = fmaxf((float)B + b1b.y, 0.0f);
        lane_stats<2>(v2, m, rs);   // LN2
        FENCE();
        V1[2 * l]     = (float)(((double)v2[0] - m) * rs) * g2b.x + c2b.x;
        V1[2 * l + 1] = (float)(((double)v2[1] - m) * rs) * g2b.y + c2b.y;
        FENCE();
        dot2<HN>(r2w + HN * HN, V1, l, A, B);   // lin2
        float r2o0 = (float)A + b2b.x;
        float r2o1 = (float)B + b2b.y;
        h0 = h0 + 0.1f * (r2o0 + h0);
        h1 = h1 + 0.1f * (r2o1 + h1);
    }

    // -------- publish h; edge MLP e1 on [hf, hf] (hf = h/256, exact pow2) ----
    *reinterpret_cast<float2*>(&V0[2 * l]) = make_float2(h0, h1);
    FENCE();
    {
        double A1, B1, A2, B2;
        dot2<HN>(e1w, V0, l, A1, B1);             // rows 0..127 (first copy)
        dot2<HN>(e1w + HN * HN, V0, l, A2, B2);   // rows 128..255 (second copy)
        double As = (A1 + A2) * 0.00390625;
        double Bs = (B1 + B2) * 0.00390625;
        float v2[2];
        v2[0] = fmaxf((float)As + e1b2.x, 0.0f);
        v2[1] = fmaxf((float)Bs + e1b2.y, 0.0f);
        double m, rs;
        lane_stats<2>(v2, m, rs);
        FENCE();
        V1[2 * l]     = (float)(((double)v2[0] - m) * rs) * eg2.x + eb2.x;
        V1[2 * l + 1] = (float)(((double)v2[1] - m) * rs) * eg2.y + eb2.y;
    }
    FENCE();

    // -------- e2: [128]->[2] --------
    {
        double p0 = (double)V1[l] * (double)e2wA.x;
        p0 = fma((double)V1[l + 64], (double)e2wB.x, p0);
        double p1 = (double)V1[l] * (double)e2wA.y;
        p1 = fma((double)V1[l + 64], (double)e2wB.y, p1);
#pragma unroll
        for (int s = 1; s < 64; s <<= 1) {
            p0 += __shfl_xor(p0, s, 64);
            p1 += __shfl_xor(p1, s, 64);
        }
        if (l == 0) {
            out_logits[b * 2]     = (float)p0 + e2b[0];
            out_logits[b * 2 + 1] = (float)p1 + e2b[1];
        }
    }
}

// ---------------- per-pair gumbel decisions + scatter ----------------
__device__ __forceinline__ int rowbase(int i) { return (i * (2 * NNODE - 1 - i)) >> 1; }

__global__ __launch_bounds__(256) void edges_kernel(const float* __restrict__ lg,
                                                    const float* __restrict__ tptr,
                                                    float* __restrict__ out)
{
    int q = blockIdx.x * blockDim.x + threadIdx.x;
    if (q >= NQ) return;
    // diagonal zeros (poison-safe: every output element is written each call)
    if (q < BN * NNODE) {
        int bb = q >> 8, ii = q & 255;
        out[(bb << 16) | (ii << 8) | ii] = 0.0f;
    }
    float temp = fminf(fmaxf(tptr[0], 0.1f), 2.0f);

    int b = q / NPAIR;
    int p = q - b * NPAIR;
    double disc = 261121.0 - 8.0 * (double)p;  // 511^2 - 8p
    int i = (int)((511.0 - sqrt(disc)) * 0.5);
    if (i < 0) i = 0;
    if (i > NNODE - 2) i = NNODE - 2;
    while (rowbase(i + 1) <= p) ++i;
    while (rowbase(i) > p) --i;
    int j = p - rowbase(i) + i + 1;

    uint32_t w0 = bits_partitionable((uint32_t)(2 * q));
    uint32_t w1 = bits_partitionable((uint32_t)(2 * q + 1));

    float u0 = bits_to_u(w0), u1 = bits_to_u(w1);
    float g0 = (float)(-log(-log((double)u0)));
    float g1 = (float)(-log(-log((double)u1)));
    float l0 = lg[2 * b], l1 = lg[2 * b + 1];
    float A0 = (l0 + g0) / temp, A1 = (l1 + g1) / temp;
    float mx = fmaxf(A0, A1);
    float e0 = expf(A0 - mx), e1 = expf(A1 - mx);
    float ssum = e0 + e1;
    float y0 = e0 / ssum, y1 = e1 / ssum;
    float xe = (y0 >= y1) ? 1.0f : 0.0f;
    out[(b << 16) | (i << 8) | j] = xe;
    out[(b << 16) | (j << 8) | i] = xe;
}

extern "C" void kernel_launch(void* const* d_in, const int* in_sizes, int n_in,
                              void* d_out, int out_size, void* d_ws, size_t ws_size,
                              hipStream_t stream)
{
    const float* x    = (const float*)d_in[0];
    const float* st   = (const float*)d_in[1];
    const float* ipw  = (const float*)d_in[2];
    const float* ipb  = (const float*)d_in[3];
    const float* ipg  = (const float*)d_in[4];
    const float* ipbb = (const float*)d_in[5];
    const float* drw  = (const float*)d_in[6];
    const float* drb  = (const float*)d_in[7];
    const float* drg  = (const float*)d_in[8];
    const float* drbb = (const float*)d_in[9];
    const float* r1w  = (const float*)d_in[10];
    const float* r1b  = (const float*)d_in[11];
    const float* r2w  = (const float*)d_in[12];
    const float* r2b  = (const float*)d_in[13];
    const float* n1g  = (const float*)d_in[14];
    const float* n1b  = (const float*)d_in[15];
    const float* n2g  = (const float*)d_in[16];
    const float* n2b  = (const float*)d_in[17];
    // d_in[18] attn_w, d_in[19] attn_b: unused (softmax over identical nodes is uniform)
    const float* e1w  = (const float*)d_in[20];
    const float* e1b  = (const float*)d_in[21];
    const float* eg   = (const float*)d_in[22];
    const float* eb   = (const float*)d_in[23];
    const float* e2w  = (const float*)d_in[24];
    const float* e2b  = (const float*)d_in[25];
    const float* temp = (const float*)d_in[26];
    float* out = (float*)d_out;
    float* lg  = (float*)d_ws;   // 32 floats: per-batch logits

    hipLaunchKernelGGL(logits_kernel, dim3(BN), dim3(64), 0, stream,
        x, st, ipw, ipb, ipg, ipbb, drw, drb, drg, drbb,
        r1w, r1b, r2w, r2b, n1g, n1b, n2g, n2b,
        e1w, e1b, eg, eb, e2w, e2b, lg);
    hipLaunchKernelGGL(edges_kernel, dim3((NQ + 255) / 256), dim3(256), 0, stream,
        lg, temp, out);
}

// Round 8
// 32.573 us; speedup vs baseline: 1.4331x; 1.4331x over previous
//
#include <hip/hip_runtime.h>
#include <stdint.h>
#include <math.h>

#define BN 16
#define LATN 64
#define STATSN 7
#define ZN 71
#define HN 128
#define H2N 256
#define NNODE 256
#define NPAIR 32640            // N*(N-1)/2
#define NQ 522240              // BN*NPAIR
#define NT 512                 // logits block size (8 waves)

// Raw barrier: drain LDS only (lgkmcnt); leave global prefetches in flight.
#define BARRIER() asm volatile("s_waitcnt lgkmcnt(0)\n\ts_barrier" ::: "memory")

// ---------------- Threefry-2x32, 20 rounds, key = (0, 42) ----------------
__device__ __forceinline__ void tf2x32(uint32_t x0, uint32_t x1,
                                       uint32_t& o0, uint32_t& o1) {
    const uint32_t ks0 = 0u, ks1 = 42u, ks2 = 0x1BD11BF0u;  // 0^42^0x1BD11BDA
    x0 += ks0; x1 += ks1;
#define TFRND(r) { x0 += x1; x1 = (x1 << (r)) | (x1 >> (32 - (r))); x1 ^= x0; }
    TFRND(13) TFRND(15) TFRND(26) TFRND(6)
    x0 += ks1; x1 += ks2 + 1u;
    TFRND(17) TFRND(29) TFRND(16) TFRND(24)
    x0 += ks2; x1 += ks0 + 2u;
    TFRND(13) TFRND(15) TFRND(26) TFRND(6)
    x0 += ks0; x1 += ks1 + 3u;
    TFRND(17) TFRND(29) TFRND(16) TFRND(24)
    x0 += ks1; x1 += ks2 + 4u;
    TFRND(13) TFRND(15) TFRND(26) TFRND(6)
    x0 += ks2; x1 += ks0 + 5u;
#undef TFRND
    o0 = x0; o1 = x1;
}

__device__ __forceinline__ uint32_t bits_partitionable(uint32_t m) {
    uint32_t o0, o1;
    tf2x32(0u, m, o0, o1);
    return o0 ^ o1;
}

__device__ __forceinline__ float bits_to_u(uint32_t w) {
    float f = __uint_as_float((w >> 9) | 0x3f800000u) - 1.0f;
    const float mn = 1e-9f;
    return fmaxf(mn, f * (1.0f - mn) + mn);
}

// ---------------- register-resident weight slice (512 threads) ----------------
template<int K, int O>
struct WS {
    static constexpr int C    = NT / O;
    static constexpr int KC   = (K + C - 1) / C;
    static constexpr int LOGO = (O == 256) ? 8 : 7;
    float w[KC];
    __device__ __forceinline__ void load(const float* __restrict__ W, int t) {
        const int out = t & (O - 1);
        const int k0 = (t >> LOGO) * KC;
#pragma unroll
        for (int i = 0; i < KC; ++i) {
            const int k = k0 + i;
            w[i] = ((K % C == 0) || k < K) ? W[k * O + out] : 0.0f;
        }
    }
    // r3-r6 verified fma pairing (a0/a1 alternate, a0+a1 combine)
    __device__ __forceinline__ double dot(const float* __restrict__ vin, int t) const {
        const int k0 = (t >> LOGO) * KC;
        double a0 = 0.0, a1 = 0.0;
#pragma unroll
        for (int i = 0; i < KC; i += 2) {
            a0 = fma((double)vin[k0 + i], (double)w[i], a0);
            if (i + 1 < KC) a1 = fma((double)vin[k0 + i + 1], (double)w[i + 1], a1);
        }
        return a0 + a1;
    }
    __device__ __forceinline__ double dot_mask127(const float* __restrict__ vin, int t) const {
        const int k0 = (t >> LOGO) * KC;
        double a0 = 0.0, a1 = 0.0;
#pragma unroll
        for (int i = 0; i < KC; i += 2) {
            a0 = fma((double)vin[(k0 + i) & 127], (double)w[i], a0);
            if (i + 1 < KC) a1 = fma((double)vin[(k0 + i + 1) & 127], (double)w[i + 1], a1);
        }
        return a0 + a1;
    }
};

// wave0 LN stats: butterfly; rsqrt = f32 seed + 2 f64 Newton steps (~1e-16 rel)
template<int NV>
__device__ __forceinline__ void w0_stats(const float* v, double& m, double& rs) {
    double a = 0.0, q = 0.0;
#pragma unroll
    for (int i = 0; i < NV; ++i) {
        a += (double)v[i];
        q += (double)v[i] * (double)v[i];
    }
#pragma unroll
    for (int s = 1; s < 64; s <<= 1) {
        a += __shfl_xor(a, s, 64);
        q += __shfl_xor(q, s, 64);
    }
    constexpr double O = (double)(NV * 64);
    m = a * (1.0 / O);
    const double d = q * (1.0 / O) - m * m + 1e-5;
    double r = (double)rsqrtf((float)d);
    r = r * (1.5 - 0.5 * d * r * r);
    r = r * (1.5 - 0.5 * d * r * r);
    rs = r;
}

__global__ __launch_bounds__(NT, 1) void logits_kernel(
    const float* __restrict__ x, const float* __restrict__ st,
    const float* __restrict__ ipw, const float* __restrict__ ipb,
    const float* __restrict__ ipg, const float* __restrict__ ipbb,
    const float* __restrict__ drw, const float* __restrict__ drb,
    const float* __restrict__ drg, const float* __restrict__ drbb,
    const float* __restrict__ r1w, const float* __restrict__ r1b,
    const float* __restrict__ r2w, const float* __restrict__ r2b,
    const float* __restrict__ n1g, const float* __restrict__ n1b,
    const float* __restrict__ n2g, const float* __restrict__ n2b,
    const float* __restrict__ e1w, const float* __restrict__ e1b,
    const float* __restrict__ eg,  const float* __restrict__ eb,
    const float* __restrict__ e2w, const float* __restrict__ e2b,
    float* __restrict__ out_logits)
{
    __shared__ __align__(16) float V0[H2N];
    __shared__ __align__(16) float V1[H2N];
    __shared__ double dpart[NT];
    const int t = threadIdx.x;
    const int b = blockIdx.x;
    const int l = t & 63;
    const bool w0 = (t < 64);

    // -------- prologue: first weight slice + wave0 epilogue params --------
    WS<ZN, H2N> w_ip;  w_ip.load(ipw, t);

    float ipbR[4], ipgR[4], ipbbR[4];
    float drbR[2], drgR[2], drbbR[2];
    float b1aR[2], g1aR[2], c1aR[2], g2aR[2], c2aR[2], b2aR[2];
    float b1bR[2], g1bR[2], c1bR[2], g2bR[2], c2bR[2], b2bR[2];
    float e1bR[2], egR[2], ebR[2], e2w0R[2], e2w1R[2];
    float e2b0 = 0.0f, e2b1 = 0.0f;
    if (w0) {
#pragma unroll
        for (int i = 0; i < 4; ++i) {
            const int o = l + 64 * i;
            ipbR[i] = ipb[o]; ipgR[i] = ipg[o]; ipbbR[i] = ipbb[o];
        }
#pragma unroll
        for (int i = 0; i < 2; ++i) {
            const int o = l + 64 * i;
            drbR[i] = drb[o]; drgR[i] = drg[o]; drbbR[i] = drbb[o];
            b1aR[i] = r1b[o];      g1aR[i] = n1g[o];      c1aR[i] = n1b[o];
            g2aR[i] = n2g[o];      c2aR[i] = n2b[o];      b2aR[i] = r2b[o];
            b1bR[i] = r1b[HN + o]; g1bR[i] = n1g[HN + o]; c1bR[i] = n1b[HN + o];
            g2bR[i] = n2g[HN + o]; c2bR[i] = n2b[HN + o]; b2bR[i] = r2b[HN + o];
            e1bR[i] = e1b[o]; egR[i] = eg[o]; ebR[i] = eb[o];
            e2w0R[i] = e2w[2 * o];
            e2w1R[i] = e2w[2 * o + 1];
        }
        e2b0 = e2b[0]; e2b1 = e2b[1];
    }

    // -------- stage z (zero-padded to 256) --------
    if (t < LATN)      V0[t] = x[b * LATN + t];
    else if (t < ZN)   V0[t] = st[b * STATSN + (t - LATN)];
    else if (t < H2N)  V0[t] = 0.0f;
    BARRIER();                                     // B0

    float h0 = 0.0f, h1 = 0.0f;   // running h, lives in wave0 regs only

    // -------- ip: [71]->relu->LN(256) -> V1 --------
    WS<H2N, HN> w_dr;  w_dr.load(drw, t);          // prefetch
    dpart[t] = w_ip.dot(V0, t);
    BARRIER();                                     // B1
    WS<HN, HN> w_r1a;  w_r1a.load(r1w, t);         // prefetch
    if (w0) {
        float v[4];
#pragma unroll
        for (int i = 0; i < 4; ++i) {
            const int o = l + 64 * i;
            double ca = 0.0;
            ca += dpart[o];
            ca += dpart[o + 256];
            v[i] = fmaxf((float)ca + ipbR[i], 0.0f);
        }
        double m, rs; w0_stats<4>(v, m, rs);
#pragma unroll
        for (int i = 0; i < 4; ++i) {
            const int o = l + 64 * i;
            V1[o] = (float)(((double)v[i] - m) * rs) * ipgR[i] + ipbbR[i];
        }
    }
    BARRIER();                                     // B2

    // -------- dr: [256]->[128], relu, LN -> h (regs) ; fused LN1a -> V1 ------
    dpart[t] = w_dr.dot(V1, t);
    BARRIER();                                     // B3
    WS<HN, HN> w_r2a;  w_r2a.load(r2w, t);         // prefetch
    if (w0) {
        float v[2];
#pragma unroll
        for (int i = 0; i < 2; ++i) {
            const int o = l + 64 * i;
            double ca = 0.0;
#pragma unroll
            for (int cc = 0; cc < 4; ++cc) ca += dpart[o + cc * HN];
            v[i] = fmaxf((float)ca + drbR[i], 0.0f);
        }
        double m, rs; w0_stats<2>(v, m, rs);
        h0 = (float)(((double)v[0] - m) * rs) * drgR[0] + drbbR[0];
        h1 = (float)(((double)v[1] - m) * rs) * drgR[1] + drbbR[1];
        float hv[2] = {h0, h1};
        double m1, rs1; w0_stats<2>(hv, m1, rs1);  // LN1a fused
        V1[l]      = (float)(((double)h0 - m1) * rs1) * g1aR[0] + c1aR[0];
        V1[l + 64] = (float)(((double)h1 - m1) * rs1) * g1aR[1] + c1aR[1];
    }
    BARRIER();                                     // B4

    // -------- res0 lin1 + relu + LN2 -> V1 --------
    dpart[t] = w_r1a.dot(V1, t);
    BARRIER();                                     // B5
    WS<HN, HN> w_r1b;  w_r1b.load(r1w + HN * HN, t);   // prefetch
    if (w0) {
        float v[2];
#pragma unroll
        for (int i = 0; i < 2; ++i) {
            const int o = l + 64 * i;
            double ca = 0.0;
#pragma unroll
            for (int cc = 0; cc < 4; ++cc) ca += dpart[o + cc * HN];
            v[i] = fmaxf((float)ca + b1aR[i], 0.0f);
        }
        double m, rs; w0_stats<2>(v, m, rs);
        V1[l]      = (float)(((double)v[0] - m) * rs) * g2aR[0] + c2aR[0];
        V1[l + 64] = (float)(((double)v[1] - m) * rs) * g2aR[1] + c2aR[1];
    }
    BARRIER();                                     // B6

    // -------- res0 lin2 + residual; fused LN1b -> V1 --------
    dpart[t] = w_r2a.dot(V1, t);
    BARRIER();                                     // B7
    WS<HN, HN> w_r2b;  w_r2b.load(r2w + HN * HN, t);   // prefetch
    if (w0) {
        float r2o[2];
#pragma unroll
        for (int i = 0; i < 2; ++i) {
            const int o = l + 64 * i;
            double ca = 0.0;
#pragma unroll
            for (int cc = 0; cc < 4; ++cc) ca += dpart[o + cc * HN];
            r2o[i] = (float)ca + b2aR[i];
        }
        h0 = h0 + 0.1f * (r2o[0] + h0);
        h1 = h1 + 0.1f * (r2o[1] + h1);
        float hv[2] = {h0, h1};
        double m1, rs1; w0_stats<2>(hv, m1, rs1);  // LN1b fused
        V1[l]      = (float)(((double)h0 - m1) * rs1) * g1bR[0] + c1bR[0];
        V1[l + 64] = (float)(((double)h1 - m1) * rs1) * g1bR[1] + c1bR[1];
    }
    BARRIER();                                     // B8

    // -------- res1 lin1 + relu + LN2 -> V1 --------
    dpart[t] = w_r1b.dot(V1, t);
    BARRIER();                                     // B9
    WS<H2N, HN> w_e1;  w_e1.load(e1w, t);          // prefetch edge MLP
    if (w0) {
        float v[2];
#pragma unroll
        for (int i = 0; i < 2; ++i) {
            const int o = l + 64 * i;
            double ca = 0.0;
#pragma unroll
            for (int cc = 0; cc < 4; ++cc) ca += dpart[o + cc * HN];
            v[i] = fmaxf((float)ca + b1bR[i], 0.0f);
        }
        double m, rs; w0_stats<2>(v, m, rs);
        V1[l]      = (float)(((double)v[0] - m) * rs) * g2bR[0] + c2bR[0];
        V1[l + 64] = (float)(((double)v[1] - m) * rs) * g2bR[1] + c2bR[1];
    }
    BARRIER();                                     // B10

    // -------- res1 lin2 + residual -> V0 (raw h; 1/256 applied in e1 dot) ----
    dpart[t] = w_r2b.dot(V1, t);
    BARRIER();                                     // B11
    if (w0) {
        float r2o[2];
#pragma unroll
        for (int i = 0; i < 2; ++i) {
            const int o = l + 64 * i;
            double ca = 0.0;
#pragma unroll
            for (int cc = 0; cc < 4; ++cc) ca += dpart[o + cc * HN];
            r2o[i] = (float)ca + b2bR[i];
        }
        h0 = h0 + 0.1f * (r2o[0] + h0);
        h1 = h1 + 0.1f * (r2o[1] + h1);
        V0[l]      = h0;
        V0[l + 64] = h1;
    }
    BARRIER();                                     // B12

    // -------- e1 on [hf, hf] (hf = h/256, exact pow2 scale after dot) --------
    dpart[t] = w_e1.dot_mask127(V0, t) * 0.00390625;
    BARRIER();                                     // B13
    if (w0) {
        float v[2];
#pragma unroll
        for (int i = 0; i < 2; ++i) {
            const int o = l + 64 * i;
            double ca = 0.0;
#pragma unroll
            for (int cc = 0; cc < 4; ++cc) ca += dpart[o + cc * HN];
            v[i] = fmaxf((float)ca + e1bR[i], 0.0f);
        }
        double m, rs; w0_stats<2>(v, m, rs);
        const float eo0 = (float)(((double)v[0] - m) * rs) * egR[0] + ebR[0];
        const float eo1 = (float)(((double)v[1] - m) * rs) * egR[1] + ebR[1];
        // e2 head: fully in-wave, no barrier
        double p0 = (double)eo0 * (double)e2w0R[0];
        p0 = fma((double)eo1, (double)e2w0R[1], p0);
        double p1 = (double)eo0 * (double)e2w1R[0];
        p1 = fma((double)eo1, (double)e2w1R[1], p1);
#pragma unroll
        for (int s = 1; s < 64; s <<= 1) {
            p0 += __shfl_xor(p0, s, 64);
            p1 += __shfl_xor(p1, s, 64);
        }
        if (l == 0) {
            out_logits[b * 2]     = (float)p0 + e2b0;
            out_logits[b * 2 + 1] = (float)p1 + e2b1;
        }
    }
}

// ---------------- per-pair gumbel decisions + scatter ----------------
__device__ __forceinline__ int rowbase(int i) { return (i * (2 * NNODE - 1 - i)) >> 1; }

__global__ __launch_bounds__(256) void edges_kernel(const float* __restrict__ lg,
                                                    const float* __restrict__ tptr,
                                                    float* __restrict__ out)
{
    int q = blockIdx.x * blockDim.x + threadIdx.x;
    if (q >= NQ) return;
    // diagonal zeros (poison-safe: every output element is written each call)
    if (q < BN * NNODE) {
        int bb = q >> 8, ii = q & 255;
        out[(bb << 16) | (ii << 8) | ii] = 0.0f;
    }
    float temp = fminf(fmaxf(tptr[0], 0.1f), 2.0f);

    int b = q / NPAIR;
    int p = q - b * NPAIR;
    double disc = 261121.0 - 8.0 * (double)p;  // 511^2 - 8p
    int i = (int)((511.0 - sqrt(disc)) * 0.5);
    if (i < 0) i = 0;
    if (i > NNODE - 2) i = NNODE - 2;
    while (rowbase(i + 1) <= p) ++i;
    while (rowbase(i) > p) --i;
    int j = p - rowbase(i) + i + 1;

    uint32_t w0 = bits_partitionable((uint32_t)(2 * q));
    uint32_t w1 = bits_partitionable((uint32_t)(2 * q + 1));

    float u0 = bits_to_u(w0), u1 = bits_to_u(w1);
    float g0 = (float)(-log(-log((double)u0)));
    float g1 = (float)(-log(-log((double)u1)));
    float l0 = lg[2 * b], l1 = lg[2 * b + 1];
    float A0 = (l0 + g0) / temp, A1 = (l1 + g1) / temp;
    float mx = fmaxf(A0, A1);
    float e0 = expf(A0 - mx), e1 = expf(A1 - mx);
    float ssum = e0 + e1;
    float y0 = e0 / ssum, y1 = e1 / ssum;
    float xe = (y0 >= y1) ? 1.0f : 0.0f;
    out[(b << 16) | (i << 8) | j] = xe;
    out[(b << 16) | (j << 8) | i] = xe;
}

extern "C" void kernel_launch(void* const* d_in, const int* in_sizes, int n_in,
                              void* d_out, int out_size, void* d_ws, size_t ws_size,
                              hipStream_t stream)
{
    const float* x    = (const float*)d_in[0];
    const float* st   = (const float*)d_in[1];
    const float* ipw  = (const float*)d_in[2];
    const float* ipb  = (const float*)d_in[3];
    const float* ipg  = (const float*)d_in[4];
    const float* ipbb = (const float*)d_in[5];
    const float* drw  = (const float*)d_in[6];
    const float* drb  = (const float*)d_in[7];
    const float* drg  = (const float*)d_in[8];
    const float* drbb = (const float*)d_in[9];
    const float* r1w  = (const float*)d_in[10];
    const float* r1b  = (const float*)d_in[11];
    const float* r2w  = (const float*)d_in[12];
    const float* r2b  = (const float*)d_in[13];
    const float* n1g  = (const float*)d_in[14];
    const float* n1b  = (const float*)d_in[15];
    const float* n2g  = (const float*)d_in[16];
    const float* n2b  = (const float*)d_in[17];
    // d_in[18] attn_w, d_in[19] attn_b: unused (softmax over identical nodes is uniform)
    const float* e1w  = (const float*)d_in[20];
    const float* e1b  = (const float*)d_in[21];
    const float* eg   = (const float*)d_in[22];
    const float* eb   = (const float*)d_in[23];
    const float* e2w  = (const float*)d_in[24];
    const float* e2b  = (const float*)d_in[25];
    const float* temp = (const float*)d_in[26];
    float* out = (float*)d_out;
    float* lg  = (float*)d_ws;   // 32 floats: per-batch logits

    hipLaunchKernelGGL(logits_kernel, dim3(BN), dim3(NT), 0, stream,
        x, st, ipw, ipb, ipg, ipbb, drw, drb, drg, drbb,
        r1w, r1b, r2w, r2b, n1g, n1b, n2g, n2b,
        e1w, e1b, eg, eb, e2w, e2b, lg);
    hipLaunchKernelGGL(edges_kernel, dim3((NQ + 255) / 256), dim3(256), 0, stream,
        lg, temp, out);
}

// Round 9
// 28.946 us; speedup vs baseline: 1.6127x; 1.1253x over previous
//
#include <hip/hip_runtime.h>
#include <stdint.h>
#include <math.h>

#define BN 16
#define LATN 64
#define STATSN 7
#define ZN 71
#define HN 128
#define H2N 256
#define NNODE 256
#define NPAIR 32640            // N*(N-1)/2
#define NQ 522240              // BN*NPAIR
#define NT 1024                // logits block size (16 waves)

// Raw barrier: drain LDS only (lgkmcnt); leave global prefetches in flight.
#define BARRIER() asm volatile("s_waitcnt lgkmcnt(0)\n\ts_barrier" ::: "memory")

// ---------------- Threefry-2x32, 20 rounds, key = (0, 42) ----------------
__device__ __forceinline__ void tf2x32(uint32_t x0, uint32_t x1,
                                       uint32_t& o0, uint32_t& o1) {
    const uint32_t ks0 = 0u, ks1 = 42u, ks2 = 0x1BD11BF0u;  // 0^42^0x1BD11BDA
    x0 += ks0; x1 += ks1;
#define TFRND(r) { x0 += x1; x1 = (x1 << (r)) | (x1 >> (32 - (r))); x1 ^= x0; }
    TFRND(13) TFRND(15) TFRND(26) TFRND(6)
    x0 += ks1; x1 += ks2 + 1u;
    TFRND(17) TFRND(29) TFRND(16) TFRND(24)
    x0 += ks2; x1 += ks0 + 2u;
    TFRND(13) TFRND(15) TFRND(26) TFRND(6)
    x0 += ks0; x1 += ks1 + 3u;
    TFRND(17) TFRND(29) TFRND(16) TFRND(24)
    x0 += ks1; x1 += ks2 + 4u;
    TFRND(13) TFRND(15) TFRND(26) TFRND(6)
    x0 += ks2; x1 += ks0 + 5u;
#undef TFRND
    o0 = x0; o1 = x1;
}

__device__ __forceinline__ uint32_t bits_partitionable(uint32_t m) {
    uint32_t o0, o1;
    tf2x32(0u, m, o0, o1);
    return o0 ^ o1;
}

__device__ __forceinline__ float bits_to_u(uint32_t w) {
    float f = __uint_as_float((w >> 9) | 0x3f800000u) - 1.0f;
    const float mn = 1e-9f;
    return fmaxf(mn, f * (1.0f - mn) + mn);
}

// ---------------- register-resident weight slice (1024 threads) ----------------
template<int K, int O>
struct WS {
    static constexpr int C    = NT / O;      // 4 for O=256, 8 for O=128
    static constexpr int KC   = (K + C - 1) / C;
    static constexpr int LOGO = (O == 256) ? 8 : 7;
    float w[KC];
    __device__ __forceinline__ void load(const float* __restrict__ W, int t) {
        const int out = t & (O - 1);
        const int k0 = (t >> LOGO) * KC;
#pragma unroll
        for (int i = 0; i < KC; ++i) {
            const int k = k0 + i;
            w[i] = ((K % C == 0) || k < K) ? W[k * O + out] : 0.0f;
        }
    }
    // r3/r6-verified fma pairing (a0/a1 alternate, a0+a1 combine)
    __device__ __forceinline__ double dot(const float* __restrict__ vin, int t) const {
        const int k0 = (t >> LOGO) * KC;
        double a0 = 0.0, a1 = 0.0;
#pragma unroll
        for (int i = 0; i < KC; i += 2) {
            a0 = fma((double)vin[k0 + i], (double)w[i], a0);
            if (i + 1 < KC) a1 = fma((double)vin[k0 + i + 1], (double)w[i + 1], a1);
        }
        return a0 + a1;
    }
    __device__ __forceinline__ double dot_mask127(const float* __restrict__ vin, int t) const {
        const int k0 = (t >> LOGO) * KC;
        double a0 = 0.0, a1 = 0.0;
#pragma unroll
        for (int i = 0; i < KC; i += 2) {
            a0 = fma((double)vin[(k0 + i) & 127], (double)w[i], a0);
            if (i + 1 < KC) a1 = fma((double)vin[(k0 + i + 1) & 127], (double)w[i + 1], a1);
        }
        return a0 + a1;
    }
};

// wave0 LN stats: butterfly; rsqrt = f32 seed + 2 f64 Newton steps (r8-verified)
template<int NV>
__device__ __forceinline__ void w0_stats(const float* v, double& m, double& rs) {
    double a = 0.0, q = 0.0;
#pragma unroll
    for (int i = 0; i < NV; ++i) {
        a += (double)v[i];
        q += (double)v[i] * (double)v[i];
    }
#pragma unroll
    for (int s = 1; s < 64; s <<= 1) {
        a += __shfl_xor(a, s, 64);
        q += __shfl_xor(q, s, 64);
    }
    constexpr double O = (double)(NV * 64);
    m = a * (1.0 / O);
    const double d = q * (1.0 / O) - m * m + 1e-5;
    double r = (double)rsqrtf((float)d);
    r = r * (1.5 - 0.5 * d * r * r);
    r = r * (1.5 - 0.5 * d * r * r);
    rs = r;
}

// epilogue-parameter LDS layout (floats)
#define P_IPB   0
#define P_IPG   256
#define P_IPBB  512
#define P_DRB   768
#define P_DRG   896
#define P_DRBB  1024
#define P_R1B   1152   /* 256: both layers */
#define P_N1G   1408
#define P_N1B   1664
#define P_N2G   1920
#define P_N2B   2176
#define P_R2B   2432
#define P_E1B   2688
#define P_EG    2816
#define P_EB    2944
#define P_E2W   3072   /* 256 */
#define P_E2B   3328   /* 2 */
#define P_SIZE  3332

__global__ __launch_bounds__(NT, 1) void logits_kernel(
    const float* __restrict__ x, const float* __restrict__ st,
    const float* __restrict__ ipw, const float* __restrict__ ipb,
    const float* __restrict__ ipg, const float* __restrict__ ipbb,
    const float* __restrict__ drw, const float* __restrict__ drb,
    const float* __restrict__ drg, const float* __restrict__ drbb,
    const float* __restrict__ r1w, const float* __restrict__ r1b,
    const float* __restrict__ r2w, const float* __restrict__ r2b,
    const float* __restrict__ n1g, const float* __restrict__ n1b,
    const float* __restrict__ n2g, const float* __restrict__ n2b,
    const float* __restrict__ e1w, const float* __restrict__ e1b,
    const float* __restrict__ eg,  const float* __restrict__ eb,
    const float* __restrict__ e2w, const float* __restrict__ e2b,
    float* __restrict__ out_logits)
{
    __shared__ __align__(16) float V0[H2N];
    __shared__ __align__(16) float V1[H2N];
    __shared__ double dpart[NT];
    __shared__ float P[P_SIZE];
    const int t = threadIdx.x;
    const int b = blockIdx.x;
    const int l = t & 63;
    const bool w0 = (t < 64);

    // weight slices, loads issued ~2 phases ahead of use
    WS<ZN, H2N> w_ip;
    WS<H2N, HN> w_dr;
    WS<HN, HN>  w_r1a, w_r2a, w_r1b, w_r2b;
    WS<H2N, HN> w_e1;

    // -------- prologue: params -> LDS, z -> V0, first two weight slices ------
    w_ip.load(ipw, t);
    w_dr.load(drw, t);
    if (t < 256) {
        P[P_IPB + t] = ipb[t];  P[P_IPG + t] = ipg[t];  P[P_IPBB + t] = ipbb[t];
        P[P_R1B + t] = r1b[t];  P[P_N1G + t] = n1g[t];  P[P_N1B + t] = n1b[t];
        P[P_N2G + t] = n2g[t];  P[P_N2B + t] = n2b[t];  P[P_R2B + t] = r2b[t];
        P[P_E2W + t] = e2w[t];
    } else if (t < 384) {
        const int i = t - 256;
        P[P_DRB + i] = drb[i];  P[P_DRG + i] = drg[i];  P[P_DRBB + i] = drbb[i];
        P[P_E1B + i] = e1b[i];  P[P_EG + i] = eg[i];    P[P_EB + i] = eb[i];
    } else if (t < 386) {
        P[P_E2B + (t - 384)] = e2b[t - 384];
    }
    if (t < LATN)      V0[t] = x[b * LATN + t];
    else if (t < ZN)   V0[t] = st[b * STATSN + (t - LATN)];
    else if (t < H2N)  V0[t] = 0.0f;     // zero-pad so padded w entries hit 0
    BARRIER();                                     // B0

    float h0 = 0.0f, h1 = 0.0f;   // running h, wave0 regs only

    // -------- ip: [71]->relu->LN(256) -> V1 --------
    dpart[t] = w_ip.dot(V0, t);
    BARRIER();                                     // B1
    w_r1a.load(r1w, t);                            // prefetch (used B4-B5)
    if (w0) {
        float v[4];
#pragma unroll
        for (int i = 0; i < 4; ++i) {
            const int o = l + 64 * i;
            double ca = 0.0;
#pragma unroll
            for (int cc = 0; cc < 4; ++cc) ca += dpart[o + cc * H2N];
            v[i] = fmaxf((float)ca + P[P_IPB + o], 0.0f);
        }
        double m, rs; w0_stats<4>(v, m, rs);
#pragma unroll
        for (int i = 0; i < 4; ++i) {
            const int o = l + 64 * i;
            V1[o] = (float)(((double)v[i] - m) * rs) * P[P_IPG + o] + P[P_IPBB + o];
        }
    }
    BARRIER();                                     // B2

    // -------- dr: [256]->[128], relu, LN -> h (regs); fused LN1a -> V1 -------
    dpart[t] = w_dr.dot(V1, t);
    BARRIER();                                     // B3
    w_r2a.load(r2w, t);                            // prefetch (used B6-B7)
    if (w0) {
        float v[2];
#pragma unroll
        for (int i = 0; i < 2; ++i) {
            const int o = l + 64 * i;
            double ca = 0.0;
#pragma unroll
            for (int cc = 0; cc < 8; ++cc) ca += dpart[o + cc * HN];
            v[i] = fmaxf((float)ca + P[P_DRB + o], 0.0f);
        }
        double m, rs; w0_stats<2>(v, m, rs);
        h0 = (float)(((double)v[0] - m) * rs) * P[P_DRG + l] + P[P_DRBB + l];
        h1 = (float)(((double)v[1] - m) * rs) * P[P_DRG + l + 64] + P[P_DRBB + l + 64];
        float hv[2] = {h0, h1};
        double m1, rs1; w0_stats<2>(hv, m1, rs1);  // LN1a fused
        V1[l]      = (float)(((double)h0 - m1) * rs1) * P[P_N1G + l] + P[P_N1B + l];
        V1[l + 64] = (float)(((double)h1 - m1) * rs1) * P[P_N1G + l + 64] + P[P_N1B + l + 64];
    }
    BARRIER();                                     // B4

    // -------- res0 lin1 + relu + LN2 -> V1 --------
    dpart[t] = w_r1a.dot(V1, t);
    BARRIER();                                     // B5
    w_r1b.load(r1w + HN * HN, t);                  // prefetch (used B8-B9)
    if (w0) {
        float v[2];
#pragma unroll
        for (int i = 0; i < 2; ++i) {
            const int o = l + 64 * i;
            double ca = 0.0;
#pragma unroll
            for (int cc = 0; cc < 8; ++cc) ca += dpart[o + cc * HN];
            v[i] = fmaxf((float)ca + P[P_R1B + o], 0.0f);
        }
        double m, rs; w0_stats<2>(v, m, rs);
        V1[l]      = (float)(((double)v[0] - m) * rs) * P[P_N2G + l] + P[P_N2B + l];
        V1[l + 64] = (float)(((double)v[1] - m) * rs) * P[P_N2G + l + 64] + P[P_N2B + l + 64];
    }
    BARRIER();                                     // B6

    // -------- res0 lin2 + residual; fused LN1b -> V1 --------
    dpart[t] = w_r2a.dot(V1, t);
    BARRIER();                                     // B7
    w_r2b.load(r2w + HN * HN, t);                  // prefetch (used B10-B11)
    if (w0) {
        float r2o[2];
#pragma unroll
        for (int i = 0; i < 2; ++i) {
            const int o = l + 64 * i;
            double ca = 0.0;
#pragma unroll
            for (int cc = 0; cc < 8; ++cc) ca += dpart[o + cc * HN];
            r2o[i] = (float)ca + P[P_R2B + o];
        }
        h0 = h0 + 0.1f * (r2o[0] + h0);
        h1 = h1 + 0.1f * (r2o[1] + h1);
        float hv[2] = {h0, h1};
        double m1, rs1; w0_stats<2>(hv, m1, rs1);  // LN1b fused
        V1[l]      = (float)(((double)h0 - m1) * rs1) * P[P_N1G + HN + l] + P[P_N1B + HN + l];
        V1[l + 64] = (float)(((double)h1 - m1) * rs1) * P[P_N1G + HN + l + 64] + P[P_N1B + HN + l + 64];
    }
    BARRIER();                                     // B8

    // -------- res1 lin1 + relu + LN2 -> V1 --------
    dpart[t] = w_r1b.dot(V1, t);
    BARRIER();                                     // B9
    w_e1.load(e1w, t);                             // prefetch (used B12-B13)
    if (w0) {
        float v[2];
#pragma unroll
        for (int i = 0; i < 2; ++i) {
            const int o = l + 64 * i;
            double ca = 0.0;
#pragma unroll
            for (int cc = 0; cc < 8; ++cc) ca += dpart[o + cc * HN];
            v[i] = fmaxf((float)ca + P[P_R1B + HN + o], 0.0f);
        }
        double m, rs; w0_stats<2>(v, m, rs);
        V1[l]      = (float)(((double)v[0] - m) * rs) * P[P_N2G + HN + l] + P[P_N2B + HN + l];
        V1[l + 64] = (float)(((double)v[1] - m) * rs) * P[P_N2G + HN + l + 64] + P[P_N2B + HN + l + 64];
    }
    BARRIER();                                     // B10

    // -------- res1 lin2 + residual -> V0 (raw h; 1/256 applied in e1 dot) ----
    dpart[t] = w_r2b.dot(V1, t);
    BARRIER();                                     // B11
    if (w0) {
        float r2o[2];
#pragma unroll
        for (int i = 0; i < 2; ++i) {
            const int o = l + 64 * i;
            double ca = 0.0;
#pragma unroll
            for (int cc = 0; cc < 8; ++cc) ca += dpart[o + cc * HN];
            r2o[i] = (float)ca + P[P_R2B + HN + o];
        }
        h0 = h0 + 0.1f * (r2o[0] + h0);
        h1 = h1 + 0.1f * (r2o[1] + h1);
        V0[l]      = h0;
        V0[l + 64] = h1;
    }
    BARRIER();                                     // B12

    // -------- e1 on [hf, hf] (hf = h/256, exact pow2 scale after dot) --------
    dpart[t] = w_e1.dot_mask127(V0, t) * 0.00390625;
    BARRIER();                                     // B13
    if (w0) {
        float v[2];
#pragma unroll
        for (int i = 0; i < 2; ++i) {
            const int o = l + 64 * i;
            double ca = 0.0;
#pragma unroll
            for (int cc = 0; cc < 8; ++cc) ca += dpart[o + cc * HN];
            v[i] = fmaxf((float)ca + P[P_E1B + o], 0.0f);
        }
        double m, rs; w0_stats<2>(v, m, rs);
        const float eo0 = (float)(((double)v[0] - m) * rs) * P[P_EG + l] + P[P_EB + l];
        const float eo1 = (float)(((double)v[1] - m) * rs) * P[P_EG + l + 64] + P[P_EB + l + 64];
        // e2 head: fully in-wave
        double p0 = (double)eo0 * (double)P[P_E2W + 2 * l];
        p0 = fma((double)eo1, (double)P[P_E2W + 2 * (l + 64)], p0);
        double p1 = (double)eo0 * (double)P[P_E2W + 2 * l + 1];
        p1 = fma((double)eo1, (double)P[P_E2W + 2 * (l + 64) + 1], p1);
#pragma unroll
        for (int s = 1; s < 64; s <<= 1) {
            p0 += __shfl_xor(p0, s, 64);
            p1 += __shfl_xor(p1, s, 64);
        }
        if (l == 0) {
            out_logits[b * 2]     = (float)p0 + P[P_E2B];
            out_logits[b * 2 + 1] = (float)p1 + P[P_E2B + 1];
        }
    }
}

// ---------------- per-pair gumbel decisions + scatter ----------------
__device__ __forceinline__ int rowbase(int i) { return (i * (2 * NNODE - 1 - i)) >> 1; }

__global__ __launch_bounds__(256) void edges_kernel(const float* __restrict__ lg,
                                                    const float* __restrict__ tptr,
                                                    float* __restrict__ out)
{
    int q = blockIdx.x * blockDim.x + threadIdx.x;
    if (q >= NQ) return;
    // diagonal zeros (poison-safe: every output element is written each call)
    if (q < BN * NNODE) {
        int bb = q >> 8, ii = q & 255;
        out[(bb << 16) | (ii << 8) | ii] = 0.0f;
    }
    float temp = fminf(fmaxf(tptr[0], 0.1f), 2.0f);

    int b = q / NPAIR;
    int p = q - b * NPAIR;
    double disc = 261121.0 - 8.0 * (double)p;  // 511^2 - 8p
    int i = (int)((511.0 - sqrt(disc)) * 0.5);
    if (i < 0) i = 0;
    if (i > NNODE - 2) i = NNODE - 2;
    while (rowbase(i + 1) <= p) ++i;
    while (rowbase(i) > p) --i;
    int j = p - rowbase(i) + i + 1;

    uint32_t w0 = bits_partitionable((uint32_t)(2 * q));
    uint32_t w1 = bits_partitionable((uint32_t)(2 * q + 1));

    float u0 = bits_to_u(w0), u1 = bits_to_u(w1);
    float g0 = (float)(-log(-log((double)u0)));
    float g1 = (float)(-log(-log((double)u1)));
    float l0 = lg[2 * b], l1 = lg[2 * b + 1];
    float A0 = (l0 + g0) / temp, A1 = (l1 + g1) / temp;
    float mx = fmaxf(A0, A1);
    float e0 = expf(A0 - mx), e1 = expf(A1 - mx);
    float ssum = e0 + e1;
    float y0 = e0 / ssum, y1 = e1 / ssum;
    float xe = (y0 >= y1) ? 1.0f : 0.0f;
    out[(b << 16) | (i << 8) | j] = xe;
    out[(b << 16) | (j << 8) | i] = xe;
}

extern "C" void kernel_launch(void* const* d_in, const int* in_sizes, int n_in,
                              void* d_out, int out_size, void* d_ws, size_t ws_size,
                              hipStream_t stream)
{
    const float* x    = (const float*)d_in[0];
    const float* st   = (const float*)d_in[1];
    const float* ipw  = (const float*)d_in[2];
    const float* ipb  = (const float*)d_in[3];
    const float* ipg  = (const float*)d_in[4];
    const float* ipbb = (const float*)d_in[5];
    const float* drw  = (const float*)d_in[6];
    const float* drb  = (const float*)d_in[7];
    const float* drg  = (const float*)d_in[8];
    const float* drbb = (const float*)d_in[9];
    const float* r1w  = (const float*)d_in[10];
    const float* r1b  = (const float*)d_in[11];
    const float* r2w  = (const float*)d_in[12];
    const float* r2b  = (const float*)d_in[13];
    const float* n1g  = (const float*)d_in[14];
    const float* n1b  = (const float*)d_in[15];
    const float* n2g  = (const float*)d_in[16];
    const float* n2b  = (const float*)d_in[17];
    // d_in[18] attn_w, d_in[19] attn_b: unused (softmax over identical nodes is uniform)
    const float* e1w  = (const float*)d_in[20];
    const float* e1b  = (const float*)d_in[21];
    const float* eg   = (const float*)d_in[22];
    const float* eb   = (const float*)d_in[23];
    const float* e2w  = (const float*)d_in[24];
    const float* e2b  = (const float*)d_in[25];
    const float* temp = (const float*)d_in[26];
    float* out = (float*)d_out;
    float* lg  = (float*)d_ws;   // 32 floats: per-batch logits

    hipLaunchKernelGGL(logits_kernel, dim3(BN), dim3(NT), 0, stream,
        x, st, ipw, ipb, ipg, ipbb, drw, drb, drg, drbb,
        r1w, r1b, r2w, r2b, n1g, n1b, n2g, n2b,
        e1w, e1b, eg, eb, e2w, e2b, lg);
    hipLaunchKernelGGL(edges_kernel, dim3((NQ + 255) / 256), dim3(256), 0, stream,
        lg, temp, out);
}